// Round 12
// baseline (530.434 us; speedup 1.0000x reference)
//
#include <hip/hip_runtime.h>
#include <math.h>

#define LRELU(v) fmaxf((v), 0.02f * (v))

typedef __attribute__((ext_vector_type(8)))  short short8;   // 8 bf16 / 4 VGPRs
typedef __attribute__((ext_vector_type(4)))  float f32x4;
typedef __attribute__((ext_vector_type(16))) float f32x16;
typedef __attribute__((ext_vector_type(2)))  int   int2v;
typedef __attribute__((ext_vector_type(4)))  int   int4v;

__device__ inline short f2bf(float f) {                       // RNE (cold paths)
    unsigned u = __builtin_bit_cast(unsigned, f);
    unsigned r = (u + 0x7FFFu + ((u >> 16) & 1u)) >> 16;
    return (short)r;
}
// 2 f32 -> packed 2x bf16 (RNE), single VALU instr. src0 -> [15:0].
__device__ inline int cvt_pk_bf16(float lo, float hi) {
    int r;
    asm("v_cvt_pk_bf16_f32 %0, %1, %2" : "=v"(r) : "v"(lo), "v"(hi));
    return r;
}
__device__ inline float exp2_asm(float x) {                   // raw v_exp_f32 = 2^x
    float r;
    asm("v_exp_f32 %0, %1" : "=v"(r) : "v"(x));
    return r;
}

#define RS5L  0.6451994329f   // (1/sqrt(5)) * log2(e): scores in log2 units

// ---------------------------------------------------------------------------
// Fully fused kernel: block = one output node.  r12 = r11 (verified 229us)
// + ONE structural change: ONE sequence per gl2 iteration (16 iters) instead
// of two, halving the y/q/k/v LDS working set: 30.7KB -> ~22KB/block =>
// LDS admits 7 blocks/CU (was 5), attacking the measured binder (latency-
// bound, 40% VALU idle, ~4 blocks TLP).  Costs accepted: 32 barriers (was
// 16) and C-phase fill 6 head-tasks/4 waves (waves 0-1: 2 heads, 2-3: 1) --
// both are hidden by the deeper TLP if residency was the binder.
// Folded-F partials: h1fp[4][16][33], one partial per wave; summed with ob2
// at gl1 Phase A.  Prefetch is 8 floats (one seq row-slice).
// Ledger: r5 bias-fold NaN; r6 prefetch@bounds5 spill (confounded); r7
// bounds5 spill; r9 no-bounds neutral; r10 barrier-fold -37us WIN; r11
// prefetch@bounds4 -13us WIN.
// Tripwire: WRITE_SIZE > 1MB (spill) or dur regression => revert to r11.
// vbf[h][e][kappa]: V rows permuted so att's C-layout regs feed the P-mfma
// A-operand directly: kappa(t) = (t&3)|((t>>1)&4)|((t<<1)&8)|(t&16).
// ---------------------------------------------------------------------------
__global__ __launch_bounds__(256, 4) void fused_kernel(
    const float* __restrict__ x2, const float* __restrict__ self_feat,
    const float* __restrict__ lw2, const float* __restrict__ lb2,
    const float* __restrict__ iw2, const float* __restrict__ ib2,
    const float* __restrict__ ow2, const float* __restrict__ ob2,
    const float* __restrict__ lw1, const float* __restrict__ lb1,
    const float* __restrict__ iw1, const float* __restrict__ ib1,
    const float* __restrict__ ow1, const float* __restrict__ ob1,
    const float* __restrict__ cw1, const float* __restrict__ cb1,
    const float* __restrict__ cw2, const float* __restrict__ cb2,
    const float* __restrict__ cw3, const float* __restrict__ cb3,
    float* __restrict__ out)
{
    __shared__ __attribute__((aligned(16))) short y_lds[32][40];
    __shared__ __attribute__((aligned(16))) short qmf[6][33][8];
    __shared__ __attribute__((aligned(16))) short kmf[6][33][8];
    __shared__ __attribute__((aligned(16))) short vbf[6][8][40];
    __shared__ __attribute__((aligned(16))) float h1fp[4][16][33]; // per-wave partial h1
    __shared__ float obar1[32];
    __shared__ float embb[32];
    __shared__ float hb1[64];
    __shared__ float hb2[64];
    __shared__ float lg[2];

    const int tid  = threadIdx.x;
    const int lane = tid & 63;
    const int w    = tid >> 6;
    const int l15  = lane & 15;
    const int lq   = lane >> 4;
    const int h5   = lane >> 5;
    const int scol = lane & 31;
    const int rowz = (lane < 32) ? scol : 32;   // lanes>=32 read the zero row

    // zero-init: full qmf/kmf (row 32 must stay zero) and vbf (e>=5 rows)
    for (int i = tid; i < 792; i += 256) { ((int*)qmf)[i] = 0; ((int*)kmf)[i] = 0; }
    for (int i = tid; i < 960; i += 256) ((int*)vbf)[i] = 0;
    if (tid < 2) obar1[30 + tid] = 0.0f;

    // ---- persistent weight fragments: LAYER 2 ONLY ----
    const int di = w & 1, si = w >> 1;
    const int jtA = (3 * w) >> 1, jtB = (3 * w + 2) >> 1;
    short8 blw2f; float lbv2v;
    {
        int d = di * 16 + l15;
        #pragma unroll
        for (int i = 0; i < 8; ++i) {
            int k = lq * 8 + i;
            blw2f[i] = f2bf((d < 30 && k < 30) ? lw2[d * 30 + k] : 0.0f);
        }
        lbv2v = (d < 30) ? lb2[d] : 0.0f;
    }
    short8 biwA2, biwB2; float ibvA2, ibvB2;
    {
        int jA = jtA * 16 + l15, jB = jtB * 16 + l15;
        #pragma unroll
        for (int i = 0; i < 8; ++i) {
            int k = lq * 8 + i;
            biwA2[i] = f2bf((jA < 90 && k < 30) ? iw2[jA * 30 + k] : 0.0f);
            biwB2[i] = f2bf((jB < 90 && k < 30) ? iw2[jB * 30 + k] : 0.0f);
        }
        ibvA2 = (jA < 90) ? ib2[jA] : 0.0f;
        ibvB2 = (jB < 90) ? ib2[jB] : 0.0f;
    }
    __syncthreads();

    const long node = (long)blockIdx.x;
    const float* xbase = x2 + node * (16L * 960);
    const float* sfp   = self_feat + node * 30;
    const int dd = (scol < 30) ? scol : 0;   // clamped d for ow2 partial loads
    const int srow = si * 16 + l15;

    // ---- prefetch seq 0's x slice into registers ----
    float xcur[8];
    {
        const float* xr = xbase + srow * 30 + lq * 8;
        #pragma unroll
        for (int i = 0; i < 8; ++i) {
            int k = lq * 8 + i;
            xcur[i] = (k < 30) ? xr[i] : 0.0f;
        }
    }

    // ================= second-hop: 16 iterations x 1 sequence =============
    for (int it = 0; it < 16; ++it) {
        float xnext[8];

        // ---- Phase A: xcur -> fragment, issue xnext loads, 1 mfma -> y ----
        {
            int4v ai;
            ai.x = cvt_pk_bf16(xcur[0], xcur[1]);
            ai.y = cvt_pk_bf16(xcur[2], xcur[3]);
            ai.z = cvt_pk_bf16(xcur[4], xcur[5]);
            ai.w = cvt_pk_bf16(xcur[6], xcur[7]);
            // xcur dead; issue next-iteration loads (hide under A+B+C)
            const int itn = (it < 15) ? it + 1 : it;
            const float* xr = xbase + itn * 960 + srow * 30 + lq * 8;
            #pragma unroll
            for (int i = 0; i < 8; ++i) {
                int k = lq * 8 + i;
                xnext[i] = (k < 30) ? xr[i] : 0.0f;
            }
            short8 af = __builtin_bit_cast(short8, ai);
            f32x4 c = {0.0f, 0.0f, 0.0f, 0.0f};
            c = __builtin_amdgcn_mfma_f32_16x16x32_bf16(af, blw2f, c, 0, 0, 0);
            float y0 = LRELU(c[0] + lbv2v), y1 = LRELU(c[1] + lbv2v);
            float y2 = LRELU(c[2] + lbv2v), y3 = LRELU(c[3] + lbv2v);
            int p01 = cvt_pk_bf16(y0, y1), p23 = cvt_pk_bf16(y2, y3);
            int row = si * 16 + lq * 4, col = di * 16 + l15;
            y_lds[row + 0][col] = (short)p01;
            y_lds[row + 1][col] = (short)(p01 >> 16);
            y_lds[row + 2][col] = (short)p23;
            y_lds[row + 3][col] = (short)(p23 >> 16);
        }
        __syncthreads();

        // ---- Phase B: qkv (3 mfma per wave), scatter q/k/vbf ----
        {
            short8 a0 = *(const short8*)&y_lds[l15][lq * 8];
            short8 a1 = *(const short8*)&y_lds[16 + l15][lq * 8];
            #pragma unroll
            for (int t = 0; t < 3; ++t) {
                int T = 3 * w + t, jt = T >> 1, si_ = T & 1;
                short8 a = si_ ? a1 : a0;
                short8 b = (jt == jtA) ? biwA2 : biwB2;
                float ibv = (jt == jtA) ? ibvA2 : ibvB2;
                f32x4 c = {0.0f, 0.0f, 0.0f, 0.0f};
                c = __builtin_amdgcn_mfma_f32_16x16x32_bf16(a, b, c, 0, 0, 0);
                int j = jt * 16 + l15;
                int s0 = si_ * 16 + lq * 4;
                if (j < 30) {
                    int h = j / 5, e = j - 5 * h;
                    int p01 = cvt_pk_bf16(c[0] + ibv, c[1] + ibv);
                    int p23 = cvt_pk_bf16(c[2] + ibv, c[3] + ibv);
                    qmf[h][s0 + 0][e] = (short)p01;
                    qmf[h][s0 + 1][e] = (short)(p01 >> 16);
                    qmf[h][s0 + 2][e] = (short)p23;
                    qmf[h][s0 + 3][e] = (short)(p23 >> 16);
                } else if (j < 60) {
                    int jj = j - 30; int h = jj / 5, e = jj - 5 * h;
                    float ibl = ibv * RS5L;
                    int p01 = cvt_pk_bf16(fmaf(c[0], RS5L, ibl), fmaf(c[1], RS5L, ibl));
                    int p23 = cvt_pk_bf16(fmaf(c[2], RS5L, ibl), fmaf(c[3], RS5L, ibl));
                    kmf[h][s0 + 0][e] = (short)p01;
                    kmf[h][s0 + 1][e] = (short)(p01 >> 16);
                    kmf[h][s0 + 2][e] = (short)p23;
                    kmf[h][s0 + 3][e] = (short)(p23 >> 16);
                } else if (j < 90) {
                    int jj = j - 60; int h = jj / 5, e = jj - 5 * h;
                    int k0 = ((s0 >> 1) & 4) | ((s0 << 1) & 8) | (s0 & 16);
                    int2v wv;
                    wv.x = cvt_pk_bf16(c[0] + ibv, c[1] + ibv);
                    wv.y = cvt_pk_bf16(c[2] + ibv, c[3] + ibv);
                    *(int2v*)&vbf[h][e][k0] = wv;
                }
            }
        }
        __syncthreads();

        // ---- Phase C (+ folded F): 6 head-tasks over 4 waves ----
        // wave 0: heads 0,1 | wave 1: heads 2,3 | wave 2: head 4 | wave 3: head 5
        {
            const int hbase = (w < 2) ? (2 * w) : (2 + w);
            const bool two = (w < 2);
            float smv0 = 0.0f, smv1 = 0.0f;
            #pragma unroll
            for (int hh = 0; hh < 2; ++hh) {
                if (hh == 1 && !two) continue;        // wave-uniform branch
                const int h = hbase + hh;
                short8 af = *(const short8*)&kmf[h][rowz][0]; // A=K*RS5L
                short8 bf = *(const short8*)&qmf[h][rowz][0]; // B=Q^T
                f32x16 c;
                #pragma unroll
                for (int r = 0; r < 16; ++r) c[r] = 0.0f;
                c = __builtin_amdgcn_mfma_f32_32x32x16_bf16(af, bf, c, 0, 0, 0);
                float m = c[0];
                #pragma unroll
                for (int r = 1; r < 16; ++r) m = fmaxf(m, c[r]);
                m = fmaxf(m, __shfl_xor(m, 32));
                float Z = 0.0f;
                #pragma unroll
                for (int r = 0; r < 16; ++r) { c[r] = exp2_asm(c[r] - m); Z += c[r]; }
                Z += __shfl_xor(Z, 32);
                float rZ = __builtin_amdgcn_rcpf(Z) * (1.0f / 32.0f);
                int4v a1i, a2i;
                a1i.x = cvt_pk_bf16(c[0] * rZ,  c[1] * rZ);
                a1i.y = cvt_pk_bf16(c[2] * rZ,  c[3] * rZ);
                a1i.z = cvt_pk_bf16(c[4] * rZ,  c[5] * rZ);
                a1i.w = cvt_pk_bf16(c[6] * rZ,  c[7] * rZ);
                a2i.x = cvt_pk_bf16(c[8] * rZ,  c[9] * rZ);
                a2i.y = cvt_pk_bf16(c[10] * rZ, c[11] * rZ);
                a2i.z = cvt_pk_bf16(c[12] * rZ, c[13] * rZ);
                a2i.w = cvt_pk_bf16(c[14] * rZ, c[15] * rZ);
                short8 b1 = *(const short8*)&vbf[h][scol & 7][8 * h5];
                short8 b2 = *(const short8*)&vbf[h][scol & 7][16 + 8 * h5];
                f32x16 P;
                #pragma unroll
                for (int r = 0; r < 16; ++r) P[r] = 0.0f;
                P = __builtin_amdgcn_mfma_f32_32x32x16_bf16(
                        __builtin_bit_cast(short8, a1i), b1, P, 0, 0, 0);
                P = __builtin_amdgcn_mfma_f32_32x32x16_bf16(
                        __builtin_bit_cast(short8, a2i), b2, P, 0, 0, 0);
                float sm = 0.0f;
                #pragma unroll
                for (int r = 0; r < 16; ++r) sm += P[r];
                sm += __shfl_xor(sm, 32);   // lane n (n<5) holds j = h*5+n
                if (hh == 0) smv0 = sm; else smv1 = sm;
            }
            // folded Phase F: partial h1 row over this wave's 5 or 10 j's
            float part = 0.0f;
            #pragma unroll
            for (int e = 0; e < 5; ++e) {
                float ov = __shfl(smv0, e);
                part = fmaf(ov, ow2[dd * 30 + hbase * 5 + e], part);
            }
            if (two) {
                #pragma unroll
                for (int e = 0; e < 5; ++e) {
                    float ov = __shfl(smv1, e);
                    part = fmaf(ov, ow2[dd * 30 + (hbase + 1) * 5 + e], part);
                }
            }
            if (lane < 30) h1fp[w][it][lane] = part;
        }
        // no post-C barrier: next Phase A touches only y_lds; the post-A
        // barrier orders C(i) reads of qmf/kmf/vbf before B(i+1) rewrites.
        #pragma unroll
        for (int i = 0; i < 8; ++i) xcur[i] = xnext[i];
    }
    __syncthreads();   // h1fp complete

    // ================= first-hop layer (S=17 masked) + MLP =================
    // layer-1 weight fragments built HERE (used once; not live in the loop)
    short8 blw1f; float lbv1v;
    {
        int d = di * 16 + l15;
        #pragma unroll
        for (int i = 0; i < 8; ++i) {
            int k = lq * 8 + i;
            blw1f[i] = f2bf((d < 30 && k < 30) ? lw1[d * 30 + k] : 0.0f);
        }
        lbv1v = (d < 30) ? lb1[d] : 0.0f;
    }
    short8 biwA1, biwB1; float ibvA1, ibvB1;
    {
        int jA = jtA * 16 + l15, jB = jtB * 16 + l15;
        #pragma unroll
        for (int i = 0; i < 8; ++i) {
            int k = lq * 8 + i;
            biwA1[i] = f2bf((jA < 90 && k < 30) ? iw1[jA * 30 + k] : 0.0f);
            biwB1[i] = f2bf((jB < 90 && k < 30) ? iw1[jB * 30 + k] : 0.0f);
        }
        ibvA1 = (jA < 90) ? ib1[jA] : 0.0f;
        ibvB1 = (jB < 90) ? ib1[jB] : 0.0f;
    }

    // ---- Phase A: rows 0..15 = h1 (= sum of 4 partials + ob2), row 16 = self ----
    {
        float xv[8];
        if (si == 0) {
            #pragma unroll
            for (int i = 0; i < 8; ++i) {
                int k = lq * 8 + i;
                xv[i] = (k < 30)
                    ? (h1fp[0][l15][k] + h1fp[1][l15][k]
                       + h1fp[2][l15][k] + h1fp[3][l15][k] + ob2[k]) : 0.0f;
            }
        } else {
            #pragma unroll
            for (int i = 0; i < 8; ++i) {
                int k = lq * 8 + i;
                xv[i] = (l15 == 0 && k < 30) ? sfp[k] : 0.0f;
            }
        }
        int4v ai;
        ai.x = cvt_pk_bf16(xv[0], xv[1]);
        ai.y = cvt_pk_bf16(xv[2], xv[3]);
        ai.z = cvt_pk_bf16(xv[4], xv[5]);
        ai.w = cvt_pk_bf16(xv[6], xv[7]);
        short8 af = __builtin_bit_cast(short8, ai);
        f32x4 c = {0.0f, 0.0f, 0.0f, 0.0f};
        c = __builtin_amdgcn_mfma_f32_16x16x32_bf16(af, blw1f, c, 0, 0, 0);
        float y0 = LRELU(c[0] + lbv1v), y1 = LRELU(c[1] + lbv1v);
        float y2 = LRELU(c[2] + lbv1v), y3 = LRELU(c[3] + lbv1v);
        int p01 = cvt_pk_bf16(y0, y1), p23 = cvt_pk_bf16(y2, y3);
        int row = si * 16 + lq * 4, col = di * 16 + l15;
        y_lds[row + 0][col] = (short)p01;
        y_lds[row + 1][col] = (short)(p01 >> 16);
        y_lds[row + 2][col] = (short)p23;
        y_lds[row + 3][col] = (short)(p23 >> 16);
    }
    __syncthreads();

    // ---- Phase B (layer-1 weights) ----
    {
        short8 a0 = *(const short8*)&y_lds[l15][lq * 8];
        short8 a1 = *(const short8*)&y_lds[16 + l15][lq * 8];
        #pragma unroll
        for (int t = 0; t < 3; ++t) {
            int T = 3 * w + t, jt = T >> 1, si_ = T & 1;
            short8 a = si_ ? a1 : a0;
            short8 b = (jt == jtA) ? biwA1 : biwB1;
            float ibv = (jt == jtA) ? ibvA1 : ibvB1;
            f32x4 c = {0.0f, 0.0f, 0.0f, 0.0f};
            c = __builtin_amdgcn_mfma_f32_16x16x32_bf16(a, b, c, 0, 0, 0);
            int j = jt * 16 + l15;
            int s0 = si_ * 16 + lq * 4;
            if (j < 30) {
                int h = j / 5, e = j - 5 * h;
                int p01 = cvt_pk_bf16(c[0] + ibv, c[1] + ibv);
                int p23 = cvt_pk_bf16(c[2] + ibv, c[3] + ibv);
                qmf[h][s0 + 0][e] = (short)p01;
                qmf[h][s0 + 1][e] = (short)(p01 >> 16);
                qmf[h][s0 + 2][e] = (short)p23;
                qmf[h][s0 + 3][e] = (short)(p23 >> 16);
            } else if (j < 60) {
                int jj = j - 30; int h = jj / 5, e = jj - 5 * h;
                float ibl = ibv * RS5L;
                int p01 = cvt_pk_bf16(fmaf(c[0], RS5L, ibl), fmaf(c[1], RS5L, ibl));
                int p23 = cvt_pk_bf16(fmaf(c[2], RS5L, ibl), fmaf(c[3], RS5L, ibl));
                kmf[h][s0 + 0][e] = (short)p01;
                kmf[h][s0 + 1][e] = (short)(p01 >> 16);
                kmf[h][s0 + 2][e] = (short)p23;
                kmf[h][s0 + 3][e] = (short)(p23 >> 16);
            } else if (j < 90) {
                int jj = j - 60; int h = jj / 5, e = jj - 5 * h;
                int k0 = ((s0 >> 1) & 4) | ((s0 << 1) & 8) | (s0 & 16);
                int2v wv;
                wv.x = cvt_pk_bf16(c[0] + ibv, c[1] + ibv);
                wv.y = cvt_pk_bf16(c[2] + ibv, c[3] + ibv);
                *(int2v*)&vbf[h][e][k0] = wv;
            }
        }
    }
    __syncthreads();

    // ---- Phase C: masked softmax (valid t < 17) + att@V + obar1 ----
    if (w < 3) {
        #pragma unroll
        for (int hh = 0; hh < 2; ++hh) {
            const int h = 2 * w + hh;
            short8 af = *(const short8*)&kmf[h][rowz][0];
            short8 bf = *(const short8*)&qmf[h][rowz][0];
            f32x16 c;
            #pragma unroll
            for (int r = 0; r < 16; ++r) c[r] = 0.0f;
            c = __builtin_amdgcn_mfma_f32_32x32x16_bf16(af, bf, c, 0, 0, 0);
            #pragma unroll
            for (int r = 0; r < 16; ++r) {
                int tr = (r & 3) + 8 * (r >> 2) + 4 * h5;
                c[r] = (tr < 17) ? c[r] : -1e30f;
            }
            float m = c[0];
            #pragma unroll
            for (int r = 1; r < 16; ++r) m = fmaxf(m, c[r]);
            m = fmaxf(m, __shfl_xor(m, 32));
            float Z = 0.0f;
            #pragma unroll
            for (int r = 0; r < 16; ++r) { c[r] = exp2_asm(c[r] - m); Z += c[r]; }
            Z += __shfl_xor(Z, 32);
            float rZ = __builtin_amdgcn_rcpf(Z) * (1.0f / 17.0f);
            int4v a1i, a2i;
            a1i.x = cvt_pk_bf16(c[0] * rZ,  c[1] * rZ);
            a1i.y = cvt_pk_bf16(c[2] * rZ,  c[3] * rZ);
            a1i.z = cvt_pk_bf16(c[4] * rZ,  c[5] * rZ);
            a1i.w = cvt_pk_bf16(c[6] * rZ,  c[7] * rZ);
            a2i.x = cvt_pk_bf16(c[8] * rZ,  c[9] * rZ);
            a2i.y = cvt_pk_bf16(c[10] * rZ, c[11] * rZ);
            a2i.z = cvt_pk_bf16(c[12] * rZ, c[13] * rZ);
            a2i.w = cvt_pk_bf16(c[14] * rZ, c[15] * rZ);
            short8 b1 = *(const short8*)&vbf[h][scol & 7][8 * h5];
            short8 b2 = *(const short8*)&vbf[h][scol & 7][16 + 8 * h5];
            f32x16 P;
            #pragma unroll
            for (int r = 0; r < 16; ++r) P[r] = 0.0f;
            P = __builtin_amdgcn_mfma_f32_32x32x16_bf16(
                    __builtin_bit_cast(short8, a1i), b1, P, 0, 0, 0);
            P = __builtin_amdgcn_mfma_f32_32x32x16_bf16(
                    __builtin_bit_cast(short8, a2i), b2, P, 0, 0, 0);
            // mean over valid s<17: regs r=0..7 (both halves) + r=8 (h5==0: s=16)
            float sm = 0.0f;
            #pragma unroll
            for (int r = 0; r < 8; ++r) sm += P[r];
            sm += (h5 == 0) ? P[8] : 0.0f;
            sm += __shfl_xor(sm, 32);
            if (lane < 5) obar1[h * 5 + lane] = sm;
        }
    }
    __syncthreads();

    // ---- Phase F: emb ----
    if (tid < 240) {
        const int d = tid >> 3, jq = tid & 7;
        f32x4 ov = *(const f32x4*)&obar1[jq * 4];
        float part = 0.0f;
        #pragma unroll
        for (int i = 0; i < 4; ++i) {
            int j = jq * 4 + i;
            if (j < 30) part = fmaf(ov[i], ow1[d * 30 + j], part);
        }
        part += __shfl_down(part, 4, 8);
        part += __shfl_down(part, 2, 8);
        part += __shfl_down(part, 1, 8);
        if (jq == 0) embb[d] = part + ob1[d];
    }
    __syncthreads();

    // ---- MLP 30 -> 64 -> 64 -> 2 + softmax ----
    {
        const int o = tid >> 2, kq = tid & 3;
        float part = 0.0f;
        #pragma unroll
        for (int i = 0; i < 8; ++i) {
            int k = kq * 8 + i;
            if (k < 30) part = fmaf(embb[k], cw1[o * 30 + k], part);
        }
        part += __shfl_down(part, 2, 4);
        part += __shfl_down(part, 1, 4);
        if (kq == 0) hb1[o] = LRELU(part + cb1[o]);
    }
    __syncthreads();
    {
        const int o = tid >> 2, kq = tid & 3;
        float part = 0.0f;
        #pragma unroll
        for (int i = 0; i < 16; ++i) {
            int k = kq * 16 + i;
            part = fmaf(hb1[k], cw2[o * 64 + k], part);
        }
        part += __shfl_down(part, 2, 4);
        part += __shfl_down(part, 1, 4);
        if (kq == 0) hb2[o] = LRELU(part + cb2[o]);
    }
    __syncthreads();
    if (tid < 128) {
        const int c = tid >> 6, k = tid & 63;
        float part = hb2[k] * cw3[c * 64 + k];
        part += __shfl_down(part, 32);
        part += __shfl_down(part, 16);
        part += __shfl_down(part, 8);
        part += __shfl_down(part, 4);
        part += __shfl_down(part, 2);
        part += __shfl_down(part, 1);
        if (k == 0) lg[c] = part + cb3[c];
    }
    __syncthreads();
    if (tid < 2) {
        float m = fmaxf(lg[0], lg[1]);
        float e0 = __expf(lg[0] - m), e1 = __expf(lg[1] - m);
        float pr = ((tid == 0) ? e0 : e1) / (e0 + e1);
        out[node * 2 + tid] = pr;
    }
}

extern "C" void kernel_launch(void* const* d_in, const int* in_sizes, int n_in,
                              void* d_out, int out_size, void* d_ws, size_t ws_size,
                              hipStream_t stream)
{
    const float* x2        = (const float*)d_in[0];
    const float* self_feat = (const float*)d_in[1];
    const float* lin_w2 = (const float*)d_in[2];
    const float* lin_b2 = (const float*)d_in[3];
    const float* in_w2  = (const float*)d_in[4];
    const float* in_b2  = (const float*)d_in[5];
    const float* out_w2 = (const float*)d_in[6];
    const float* out_b2 = (const float*)d_in[7];
    const float* lin_w1 = (const float*)d_in[8];
    const float* lin_b1 = (const float*)d_in[9];
    const float* in_w1  = (const float*)d_in[10];
    const float* in_b1  = (const float*)d_in[11];
    const float* out_w1 = (const float*)d_in[12];
    const float* out_b1 = (const float*)d_in[13];
    const float* cw1 = (const float*)d_in[14];
    const float* cb1 = (const float*)d_in[15];
    const float* cw2 = (const float*)d_in[16];
    const float* cb2 = (const float*)d_in[17];
    const float* cw3 = (const float*)d_in[18];
    const float* cb3 = (const float*)d_in[19];
    float* outp = (float*)d_out;

    fused_kernel<<<4096, 256, 0, stream>>>(
        x2, self_feat,
        lin_w2, lin_b2, in_w2, in_b2, out_w2, out_b2,
        lin_w1, lin_b1, in_w1, in_b1, out_w1, out_b1,
        cw1, cb1, cw2, cb2, cw3, cb3, outp);
}

// Round 13
// 483.608 us; speedup vs baseline: 1.0968x; 1.0968x over previous
//
#include <hip/hip_runtime.h>
#include <math.h>

#define LRELU(v) fmaxf((v), 0.02f * (v))

typedef __attribute__((ext_vector_type(8)))  short short8;   // 8 bf16 / 4 VGPRs
typedef __attribute__((ext_vector_type(4)))  float f32x4;
typedef __attribute__((ext_vector_type(16))) float f32x16;
typedef __attribute__((ext_vector_type(2)))  int   int2v;
typedef __attribute__((ext_vector_type(4)))  int   int4v;

__device__ inline short f2bf(float f) {                       // RNE (cold paths)
    unsigned u = __builtin_bit_cast(unsigned, f);
    unsigned r = (u + 0x7FFFu + ((u >> 16) & 1u)) >> 16;
    return (short)r;
}
// 2 f32 -> packed 2x bf16 (RNE), single VALU instr. src0 -> [15:0].
__device__ inline int cvt_pk_bf16(float lo, float hi) {
    int r;
    asm("v_cvt_pk_bf16_f32 %0, %1, %2" : "=v"(r) : "v"(lo), "v"(hi));
    return r;
}
__device__ inline float exp2_asm(float x) {                   // raw v_exp_f32 = 2^x
    float r;
    asm("v_exp_f32 %0, %1" : "=v"(r) : "v"(x));
    return r;
}

#define RS5L  0.6451994329f   // (1/sqrt(5)) * log2(e): scores in log2 units

// ---------------------------------------------------------------------------
// Fully fused kernel: block = one output node.  r13 = EXACT r11 restoration
// (verified best: kernel 229.5us, bench 486.9us, zero spill).
// r12 refuted the last open theory: halving LDS (30.7->22KB, admits 7
// blocks/CU) left Occupancy unchanged at ~43% and regressed dur (+40us from
// doubled barriers + worse C fill).  Occupancy is 41-44% in EVERY config
// (LDS 22-31KB, VGPR 48-64, bounds 4/5/none) => residency is HW-pinned,
// not resource-bound; TLP is not reachable from source.
// Ceiling ledger:
//   r5  bias-in-K fold          -> NaN (dropped)
//   r6  reg-prefetch@bounds5    -> 102MB spill (confounded by bounds5)
//   r7  bounds(256,5)           -> allocator clamps 48 VGPR, 37MB spill
//   r9  no launch_bounds        -> neutral (288us)
//   r10 Phase-F fold, 3->2 barriers/iter -> 279->242us WIN
//   r11 reg-prefetch@bounds4    -> 242->229.5us WIN (r6 verdict overturned)
//   r12 1-seq/iter LDS halving  -> 269.5us REGRESSION (occupancy unmoved)
// Memory is exact (FETCH~=ideal 124MB, WRITE=output-only); all matmuls on
// MFMA; conversions packed; 2 barriers/iter is the race-free minimum.
// vbf[pr][h][e][kappa]: V rows permuted so att's C-layout regs feed the
// P-mfma A-operand directly: kappa(t) = (t&3)|((t>>1)&4)|((t<<1)&8)|(t&16).
// ---------------------------------------------------------------------------
__global__ __launch_bounds__(256, 4) void fused_kernel(
    const float* __restrict__ x2, const float* __restrict__ self_feat,
    const float* __restrict__ lw2, const float* __restrict__ lb2,
    const float* __restrict__ iw2, const float* __restrict__ ib2,
    const float* __restrict__ ow2, const float* __restrict__ ob2,
    const float* __restrict__ lw1, const float* __restrict__ lb1,
    const float* __restrict__ iw1, const float* __restrict__ ib1,
    const float* __restrict__ ow1, const float* __restrict__ ob1,
    const float* __restrict__ cw1, const float* __restrict__ cb1,
    const float* __restrict__ cw2, const float* __restrict__ cb2,
    const float* __restrict__ cw3, const float* __restrict__ cb3,
    float* __restrict__ out)
{
    __shared__ __attribute__((aligned(16))) short y_lds[2][32][40];
    __shared__ __attribute__((aligned(16))) short qmf[2][6][33][8];
    __shared__ __attribute__((aligned(16))) short kmf[2][6][33][8];
    __shared__ __attribute__((aligned(16))) short vbf[2][6][8][40];
    __shared__ __attribute__((aligned(16))) float h1fp[2][16][33]; // partial h1 rows
    __shared__ float obar1[32];
    __shared__ float embb[32];
    __shared__ float hb1[64];
    __shared__ float hb2[64];
    __shared__ float lg[2];

    const int tid  = threadIdx.x;
    const int lane = tid & 63;
    const int w    = tid >> 6;
    const int l15  = lane & 15;
    const int lq   = lane >> 4;
    const int h5   = lane >> 5;
    const int scol = lane & 31;
    const int rowz = (lane < 32) ? scol : 32;   // lanes>=32 read the zero row

    // zero-init: full qmf/kmf (row 32 must stay zero) and vbf (e>=5 rows)
    for (int i = tid; i < 1584; i += 256) { ((int*)qmf)[i] = 0; ((int*)kmf)[i] = 0; }
    for (int i = tid; i < 1920; i += 256) ((int*)vbf)[i] = 0;
    if (tid < 2) obar1[30 + tid] = 0.0f;

    // ---- persistent weight fragments: LAYER 2 ONLY ----
    const int di = w & 1, si = w >> 1;
    const int jtA = (3 * w) >> 1, jtB = (3 * w + 2) >> 1;
    short8 blw2f; float lbv2v;
    {
        int d = di * 16 + l15;
        #pragma unroll
        for (int i = 0; i < 8; ++i) {
            int k = lq * 8 + i;
            blw2f[i] = f2bf((d < 30 && k < 30) ? lw2[d * 30 + k] : 0.0f);
        }
        lbv2v = (d < 30) ? lb2[d] : 0.0f;
    }
    short8 biwA2, biwB2; float ibvA2, ibvB2;
    {
        int jA = jtA * 16 + l15, jB = jtB * 16 + l15;
        #pragma unroll
        for (int i = 0; i < 8; ++i) {
            int k = lq * 8 + i;
            biwA2[i] = f2bf((jA < 90 && k < 30) ? iw2[jA * 30 + k] : 0.0f);
            biwB2[i] = f2bf((jB < 90 && k < 30) ? iw2[jB * 30 + k] : 0.0f);
        }
        ibvA2 = (jA < 90) ? ib2[jA] : 0.0f;
        ibvB2 = (jB < 90) ? ib2[jB] : 0.0f;
    }
    __syncthreads();

    const long node = (long)blockIdx.x;
    const float* xbase = x2 + node * (16L * 960);
    const float* sfp   = self_feat + node * 30;
    const int dd = (scol < 30) ? scol : 0;   // clamped d for ow2 partial loads
    const int srow = si * 16 + l15;

    // ---- prefetch it=0's x into registers ----
    float xcur[16];
    {
        #pragma unroll
        for (int pr = 0; pr < 2; ++pr) {
            const float* xr = xbase + pr * 960 + srow * 30 + lq * 8;
            #pragma unroll
            for (int i = 0; i < 8; ++i) {
                int k = lq * 8 + i;
                xcur[pr * 8 + i] = (k < 30) ? xr[i] : 0.0f;
            }
        }
    }

    // ================= second-hop: 8 iterations x 2 pairs =================
    for (int it = 0; it < 8; ++it) {
        float xnext[16];

        // ---- Phase A: xcur -> fragments, issue xnext loads, 2 mfma -> y ----
        {
            int4v aif[2];
            #pragma unroll
            for (int pr = 0; pr < 2; ++pr) {
                aif[pr].x = cvt_pk_bf16(xcur[pr * 8 + 0], xcur[pr * 8 + 1]);
                aif[pr].y = cvt_pk_bf16(xcur[pr * 8 + 2], xcur[pr * 8 + 3]);
                aif[pr].z = cvt_pk_bf16(xcur[pr * 8 + 4], xcur[pr * 8 + 5]);
                aif[pr].w = cvt_pk_bf16(xcur[pr * 8 + 6], xcur[pr * 8 + 7]);
            }
            // xcur dead; issue next-iteration loads (latency hides under A+B+C)
            const int itn = (it < 7) ? it + 1 : it;
            #pragma unroll
            for (int pr = 0; pr < 2; ++pr) {
                const float* xr = xbase + (2 * itn + pr) * 960 + srow * 30 + lq * 8;
                #pragma unroll
                for (int i = 0; i < 8; ++i) {
                    int k = lq * 8 + i;
                    xnext[pr * 8 + i] = (k < 30) ? xr[i] : 0.0f;
                }
            }
            #pragma unroll
            for (int pr = 0; pr < 2; ++pr) {
                short8 af = __builtin_bit_cast(short8, aif[pr]);
                f32x4 c = {0.0f, 0.0f, 0.0f, 0.0f};
                c = __builtin_amdgcn_mfma_f32_16x16x32_bf16(af, blw2f, c, 0, 0, 0);
                float y0 = LRELU(c[0] + lbv2v), y1 = LRELU(c[1] + lbv2v);
                float y2 = LRELU(c[2] + lbv2v), y3 = LRELU(c[3] + lbv2v);
                int p01 = cvt_pk_bf16(y0, y1), p23 = cvt_pk_bf16(y2, y3);
                int row = si * 16 + lq * 4, col = di * 16 + l15;
                y_lds[pr][row + 0][col] = (short)p01;
                y_lds[pr][row + 1][col] = (short)(p01 >> 16);
                y_lds[pr][row + 2][col] = (short)p23;
                y_lds[pr][row + 3][col] = (short)(p23 >> 16);
            }
        }
        __syncthreads();

        // ---- Phase B: qkv (3 mfma per pair per wave), scatter q/k/vbf ----
        {
            #pragma unroll
            for (int pr = 0; pr < 2; ++pr) {
                short8 a0 = *(const short8*)&y_lds[pr][l15][lq * 8];
                short8 a1 = *(const short8*)&y_lds[pr][16 + l15][lq * 8];
                #pragma unroll
                for (int t = 0; t < 3; ++t) {
                    int T = 3 * w + t, jt = T >> 1, si_ = T & 1;
                    short8 a = si_ ? a1 : a0;
                    short8 b = (jt == jtA) ? biwA2 : biwB2;
                    float ibv = (jt == jtA) ? ibvA2 : ibvB2;
                    f32x4 c = {0.0f, 0.0f, 0.0f, 0.0f};
                    c = __builtin_amdgcn_mfma_f32_16x16x32_bf16(a, b, c, 0, 0, 0);
                    int j = jt * 16 + l15;
                    int s0 = si_ * 16 + lq * 4;
                    if (j < 30) {
                        int h = j / 5, e = j - 5 * h;
                        int p01 = cvt_pk_bf16(c[0] + ibv, c[1] + ibv);
                        int p23 = cvt_pk_bf16(c[2] + ibv, c[3] + ibv);
                        qmf[pr][h][s0 + 0][e] = (short)p01;
                        qmf[pr][h][s0 + 1][e] = (short)(p01 >> 16);
                        qmf[pr][h][s0 + 2][e] = (short)p23;
                        qmf[pr][h][s0 + 3][e] = (short)(p23 >> 16);
                    } else if (j < 60) {
                        int jj = j - 30; int h = jj / 5, e = jj - 5 * h;
                        float ibl = ibv * RS5L;
                        int p01 = cvt_pk_bf16(fmaf(c[0], RS5L, ibl), fmaf(c[1], RS5L, ibl));
                        int p23 = cvt_pk_bf16(fmaf(c[2], RS5L, ibl), fmaf(c[3], RS5L, ibl));
                        kmf[pr][h][s0 + 0][e] = (short)p01;
                        kmf[pr][h][s0 + 1][e] = (short)(p01 >> 16);
                        kmf[pr][h][s0 + 2][e] = (short)p23;
                        kmf[pr][h][s0 + 3][e] = (short)(p23 >> 16);
                    } else if (j < 90) {
                        int jj = j - 60; int h = jj / 5, e = jj - 5 * h;
                        int k0 = ((s0 >> 1) & 4) | ((s0 << 1) & 8) | (s0 & 16);
                        int2v wv;
                        wv.x = cvt_pk_bf16(c[0] + ibv, c[1] + ibv);
                        wv.y = cvt_pk_bf16(c[2] + ibv, c[3] + ibv);
                        *(int2v*)&vbf[pr][h][e][k0] = wv;
                    }
                }
            }
        }
        __syncthreads();

        // ---- Phase C (+ folded F): scores + softmax + att@V + partial h1 ----
        // wave w -> pair pr = w>>1, j-group grp = w&1 (heads 3*grp..3*grp+2)
        {
            const int pr  = w >> 1;
            const int grp = w & 1;
            float smv0, smv1, smv2;
            #pragma unroll
            for (int hh = 0; hh < 3; ++hh) {
                const int h = 3 * grp + hh;
                short8 af = *(const short8*)&kmf[pr][h][rowz][0]; // A=K*RS5L
                short8 bf = *(const short8*)&qmf[pr][h][rowz][0]; // B=Q^T
                f32x16 c;
                #pragma unroll
                for (int r = 0; r < 16; ++r) c[r] = 0.0f;
                c = __builtin_amdgcn_mfma_f32_32x32x16_bf16(af, bf, c, 0, 0, 0);
                float m = c[0];
                #pragma unroll
                for (int r = 1; r < 16; ++r) m = fmaxf(m, c[r]);
                m = fmaxf(m, __shfl_xor(m, 32));
                float Z = 0.0f;
                #pragma unroll
                for (int r = 0; r < 16; ++r) { c[r] = exp2_asm(c[r] - m); Z += c[r]; }
                Z += __shfl_xor(Z, 32);
                float rZ = __builtin_amdgcn_rcpf(Z) * (1.0f / 32.0f);
                int4v a1i, a2i;
                a1i.x = cvt_pk_bf16(c[0] * rZ,  c[1] * rZ);
                a1i.y = cvt_pk_bf16(c[2] * rZ,  c[3] * rZ);
                a1i.z = cvt_pk_bf16(c[4] * rZ,  c[5] * rZ);
                a1i.w = cvt_pk_bf16(c[6] * rZ,  c[7] * rZ);
                a2i.x = cvt_pk_bf16(c[8] * rZ,  c[9] * rZ);
                a2i.y = cvt_pk_bf16(c[10] * rZ, c[11] * rZ);
                a2i.z = cvt_pk_bf16(c[12] * rZ, c[13] * rZ);
                a2i.w = cvt_pk_bf16(c[14] * rZ, c[15] * rZ);
                short8 b1 = *(const short8*)&vbf[pr][h][scol & 7][8 * h5];
                short8 b2 = *(const short8*)&vbf[pr][h][scol & 7][16 + 8 * h5];
                f32x16 P;
                #pragma unroll
                for (int r = 0; r < 16; ++r) P[r] = 0.0f;
                P = __builtin_amdgcn_mfma_f32_32x32x16_bf16(
                        __builtin_bit_cast(short8, a1i), b1, P, 0, 0, 0);
                P = __builtin_amdgcn_mfma_f32_32x32x16_bf16(
                        __builtin_bit_cast(short8, a2i), b2, P, 0, 0, 0);
                float sm = 0.0f;
                #pragma unroll
                for (int r = 0; r < 16; ++r) sm += P[r];
                sm += __shfl_xor(sm, 32);        // lane n holds value for j = h*5+n (n<5)
                if (hh == 0) smv0 = sm; else if (hh == 1) smv1 = sm; else smv2 = sm;
            }
            // folded Phase F: partial h1 row over this wave's 15 j's
            float part = 0.0f;
            #pragma unroll
            for (int hh = 0; hh < 3; ++hh) {
                float smv = (hh == 0) ? smv0 : (hh == 1) ? smv1 : smv2;
                #pragma unroll
                for (int e = 0; e < 5; ++e) {
                    float ov = __shfl(smv, e);
                    part = fmaf(ov, ow2[dd * 30 + grp * 15 + hh * 5 + e], part);
                }
            }
            if (lane < 30) h1fp[grp][2 * it + pr][lane] = part;
        }
        // no post-C barrier: next Phase A touches only y_lds; the post-A
        // barrier orders C(i) reads of qmf/kmf/vbf before B(i+1) rewrites.
        #pragma unroll
        for (int i = 0; i < 16; ++i) xcur[i] = xnext[i];
    }
    __syncthreads();   // h1fp complete

    // ================= first-hop layer (S=17 masked) + MLP =================
    // layer-1 weight fragments built HERE (used once; not live in the loop)
    short8 blw1f; float lbv1v;
    {
        int d = di * 16 + l15;
        #pragma unroll
        for (int i = 0; i < 8; ++i) {
            int k = lq * 8 + i;
            blw1f[i] = f2bf((d < 30 && k < 30) ? lw1[d * 30 + k] : 0.0f);
        }
        lbv1v = (d < 30) ? lb1[d] : 0.0f;
    }
    short8 biwA1, biwB1; float ibvA1, ibvB1;
    {
        int jA = jtA * 16 + l15, jB = jtB * 16 + l15;
        #pragma unroll
        for (int i = 0; i < 8; ++i) {
            int k = lq * 8 + i;
            biwA1[i] = f2bf((jA < 90 && k < 30) ? iw1[jA * 30 + k] : 0.0f);
            biwB1[i] = f2bf((jB < 90 && k < 30) ? iw1[jB * 30 + k] : 0.0f);
        }
        ibvA1 = (jA < 90) ? ib1[jA] : 0.0f;
        ibvB1 = (jB < 90) ? ib1[jB] : 0.0f;
    }

    // ---- Phase A: rows 0..15 = h1 (= partial0+partial1+ob2), row 16 = self ----
    {
        float xv[8];
        if (si == 0) {
            #pragma unroll
            for (int i = 0; i < 8; ++i) {
                int k = lq * 8 + i;
                xv[i] = (k < 30)
                    ? (h1fp[0][l15][k] + h1fp[1][l15][k] + ob2[k]) : 0.0f;
            }
        } else {
            #pragma unroll
            for (int i = 0; i < 8; ++i) {
                int k = lq * 8 + i;
                xv[i] = (l15 == 0 && k < 30) ? sfp[k] : 0.0f;
            }
        }
        int4v ai;
        ai.x = cvt_pk_bf16(xv[0], xv[1]);
        ai.y = cvt_pk_bf16(xv[2], xv[3]);
        ai.z = cvt_pk_bf16(xv[4], xv[5]);
        ai.w = cvt_pk_bf16(xv[6], xv[7]);
        short8 af = __builtin_bit_cast(short8, ai);
        f32x4 c = {0.0f, 0.0f, 0.0f, 0.0f};
        c = __builtin_amdgcn_mfma_f32_16x16x32_bf16(af, blw1f, c, 0, 0, 0);
        float y0 = LRELU(c[0] + lbv1v), y1 = LRELU(c[1] + lbv1v);
        float y2 = LRELU(c[2] + lbv1v), y3 = LRELU(c[3] + lbv1v);
        int p01 = cvt_pk_bf16(y0, y1), p23 = cvt_pk_bf16(y2, y3);
        int row = si * 16 + lq * 4, col = di * 16 + l15;
        y_lds[0][row + 0][col] = (short)p01;
        y_lds[0][row + 1][col] = (short)(p01 >> 16);
        y_lds[0][row + 2][col] = (short)p23;
        y_lds[0][row + 3][col] = (short)(p23 >> 16);
    }
    __syncthreads();

    // ---- Phase B (layer-1 weights) ----
    {
        short8 a0 = *(const short8*)&y_lds[0][l15][lq * 8];
        short8 a1 = *(const short8*)&y_lds[0][16 + l15][lq * 8];
        #pragma unroll
        for (int t = 0; t < 3; ++t) {
            int T = 3 * w + t, jt = T >> 1, si_ = T & 1;
            short8 a = si_ ? a1 : a0;
            short8 b = (jt == jtA) ? biwA1 : biwB1;
            float ibv = (jt == jtA) ? ibvA1 : ibvB1;
            f32x4 c = {0.0f, 0.0f, 0.0f, 0.0f};
            c = __builtin_amdgcn_mfma_f32_16x16x32_bf16(a, b, c, 0, 0, 0);
            int j = jt * 16 + l15;
            int s0 = si_ * 16 + lq * 4;
            if (j < 30) {
                int h = j / 5, e = j - 5 * h;
                int p01 = cvt_pk_bf16(c[0] + ibv, c[1] + ibv);
                int p23 = cvt_pk_bf16(c[2] + ibv, c[3] + ibv);
                qmf[0][h][s0 + 0][e] = (short)p01;
                qmf[0][h][s0 + 1][e] = (short)(p01 >> 16);
                qmf[0][h][s0 + 2][e] = (short)p23;
                qmf[0][h][s0 + 3][e] = (short)(p23 >> 16);
            } else if (j < 60) {
                int jj = j - 30; int h = jj / 5, e = jj - 5 * h;
                float ibl = ibv * RS5L;
                int p01 = cvt_pk_bf16(fmaf(c[0], RS5L, ibl), fmaf(c[1], RS5L, ibl));
                int p23 = cvt_pk_bf16(fmaf(c[2], RS5L, ibl), fmaf(c[3], RS5L, ibl));
                kmf[0][h][s0 + 0][e] = (short)p01;
                kmf[0][h][s0 + 1][e] = (short)(p01 >> 16);
                kmf[0][h][s0 + 2][e] = (short)p23;
                kmf[0][h][s0 + 3][e] = (short)(p23 >> 16);
            } else if (j < 90) {
                int jj = j - 60; int h = jj / 5, e = jj - 5 * h;
                int k0 = ((s0 >> 1) & 4) | ((s0 << 1) & 8) | (s0 & 16);
                int2v wv;
                wv.x = cvt_pk_bf16(c[0] + ibv, c[1] + ibv);
                wv.y = cvt_pk_bf16(c[2] + ibv, c[3] + ibv);
                *(int2v*)&vbf[0][h][e][k0] = wv;
            }
        }
    }
    __syncthreads();

    // ---- Phase C: masked softmax (valid t < 17) + att@V + obar1 ----
    if (w < 3) {
        #pragma unroll
        for (int hh = 0; hh < 2; ++hh) {
            const int h = 2 * w + hh;
            short8 af = *(const short8*)&kmf[0][h][rowz][0];
            short8 bf = *(const short8*)&qmf[0][h][rowz][0];
            f32x16 c;
            #pragma unroll
            for (int r = 0; r < 16; ++r) c[r] = 0.0f;
            c = __builtin_amdgcn_mfma_f32_32x32x16_bf16(af, bf, c, 0, 0, 0);
            #pragma unroll
            for (int r = 0; r < 16; ++r) {
                int tr = (r & 3) + 8 * (r >> 2) + 4 * h5;
                c[r] = (tr < 17) ? c[r] : -1e30f;
            }
            float m = c[0];
            #pragma unroll
            for (int r = 1; r < 16; ++r) m = fmaxf(m, c[r]);
            m = fmaxf(m, __shfl_xor(m, 32));
            float Z = 0.0f;
            #pragma unroll
            for (int r = 0; r < 16; ++r) { c[r] = exp2_asm(c[r] - m); Z += c[r]; }
            Z += __shfl_xor(Z, 32);
            float rZ = __builtin_amdgcn_rcpf(Z) * (1.0f / 17.0f);
            int4v a1i, a2i;
            a1i.x = cvt_pk_bf16(c[0] * rZ,  c[1] * rZ);
            a1i.y = cvt_pk_bf16(c[2] * rZ,  c[3] * rZ);
            a1i.z = cvt_pk_bf16(c[4] * rZ,  c[5] * rZ);
            a1i.w = cvt_pk_bf16(c[6] * rZ,  c[7] * rZ);
            a2i.x = cvt_pk_bf16(c[8] * rZ,  c[9] * rZ);
            a2i.y = cvt_pk_bf16(c[10] * rZ, c[11] * rZ);
            a2i.z = cvt_pk_bf16(c[12] * rZ, c[13] * rZ);
            a2i.w = cvt_pk_bf16(c[14] * rZ, c[15] * rZ);
            short8 b1 = *(const short8*)&vbf[0][h][scol & 7][8 * h5];
            short8 b2 = *(const short8*)&vbf[0][h][scol & 7][16 + 8 * h5];
            f32x16 P;
            #pragma unroll
            for (int r = 0; r < 16; ++r) P[r] = 0.0f;
            P = __builtin_amdgcn_mfma_f32_32x32x16_bf16(
                    __builtin_bit_cast(short8, a1i), b1, P, 0, 0, 0);
            P = __builtin_amdgcn_mfma_f32_32x32x16_bf16(
                    __builtin_bit_cast(short8, a2i), b2, P, 0, 0, 0);
            // mean over valid s<17: regs r=0..7 (both halves) + r=8 (h5==0: s=16)
            float sm = 0.0f;
            #pragma unroll
            for (int r = 0; r < 8; ++r) sm += P[r];
            sm += (h5 == 0) ? P[8] : 0.0f;
            sm += __shfl_xor(sm, 32);
            if (lane < 5) obar1[h * 5 + lane] = sm;
        }
    }
    __syncthreads();

    // ---- Phase F: emb ----
    if (tid < 240) {
        const int d = tid >> 3, jq = tid & 7;
        f32x4 ov = *(const f32x4*)&obar1[jq * 4];
        float part = 0.0f;
        #pragma unroll
        for (int i = 0; i < 4; ++i) {
            int j = jq * 4 + i;
            if (j < 30) part = fmaf(ov[i], ow1[d * 30 + j], part);
        }
        part += __shfl_down(part, 4, 8);
        part += __shfl_down(part, 2, 8);
        part += __shfl_down(part, 1, 8);
        if (jq == 0) embb[d] = part + ob1[d];
    }
    __syncthreads();

    // ---- MLP 30 -> 64 -> 64 -> 2 + softmax ----
    {
        const int o = tid >> 2, kq = tid & 3;
        float part = 0.0f;
        #pragma unroll
        for (int i = 0; i < 8; ++i) {
            int k = kq * 8 + i;
            if (k < 30) part = fmaf(embb[k], cw1[o * 30 + k], part);
        }
        part += __shfl_down(part, 2, 4);
        part += __shfl_down(part, 1, 4);
        if (kq == 0) hb1[o] = LRELU(part + cb1[o]);
    }
    __syncthreads();
    {
        const int o = tid >> 2, kq = tid & 3;
        float part = 0.0f;
        #pragma unroll
        for (int i = 0; i < 16; ++i) {
            int k = kq * 16 + i;
            part = fmaf(hb1[k], cw2[o * 64 + k], part);
        }
        part += __shfl_down(part, 2, 4);
        part += __shfl_down(part, 1, 4);
        if (kq == 0) hb2[o] = LRELU(part + cb2[o]);
    }
    __syncthreads();
    if (tid < 128) {
        const int c = tid >> 6, k = tid & 63;
        float part = hb2[k] * cw3[c * 64 + k];
        part += __shfl_down(part, 32);
        part += __shfl_down(part, 16);
        part += __shfl_down(part, 8);
        part += __shfl_down(part, 4);
        part += __shfl_down(part, 2);
        part += __shfl_down(part, 1);
        if (k == 0) lg[c] = part + cb3[c];
    }
    __syncthreads();
    if (tid < 2) {
        float m = fmaxf(lg[0], lg[1]);
        float e0 = __expf(lg[0] - m), e1 = __expf(lg[1] - m);
        float pr = ((tid == 0) ? e0 : e1) / (e0 + e1);
        out[node * 2 + tid] = pr;
    }
}

extern "C" void kernel_launch(void* const* d_in, const int* in_sizes, int n_in,
                              void* d_out, int out_size, void* d_ws, size_t ws_size,
                              hipStream_t stream)
{
    const float* x2        = (const float*)d_in[0];
    const float* self_feat = (const float*)d_in[1];
    const float* lin_w2 = (const float*)d_in[2];
    const float* lin_b2 = (const float*)d_in[3];
    const float* in_w2  = (const float*)d_in[4];
    const float* in_b2  = (const float*)d_in[5];
    const float* out_w2 = (const float*)d_in[6];
    const float* out_b2 = (const float*)d_in[7];
    const float* lin_w1 = (const float*)d_in[8];
    const float* lin_b1 = (const float*)d_in[9];
    const float* in_w1  = (const float*)d_in[10];
    const float* in_b1  = (const float*)d_in[11];
    const float* out_w1 = (const float*)d_in[12];
    const float* out_b1 = (const float*)d_in[13];
    const float* cw1 = (const float*)d_in[14];
    const float* cb1 = (const float*)d_in[15];
    const float* cw2 = (const float*)d_in[16];
    const float* cb2 = (const float*)d_in[17];
    const float* cw3 = (const float*)d_in[18];
    const float* cb3 = (const float*)d_in[19];
    float* outp = (float*)d_out;

    fused_kernel<<<4096, 256, 0, stream>>>(
        x2, self_feat,
        lin_w2, lin_b2, in_w2, in_b2, out_w2, out_b2,
        lin_w1, lin_b1, in_w1, in_b1, out_w1, out_b1,
        cw1, cb1, cw2, cb2, cw3, cb3, outp);
}